// Round 5
// baseline (132.271 us; speedup 1.0000x reference)
//
#include <hip/hip_runtime.h>

#define BB 32
#define SS 64
#define WW 30
#define EE 300
#define VDD 128
#define HH 32

typedef short bf16x8 __attribute__((ext_vector_type(8)));
typedef float f32x4 __attribute__((ext_vector_type(4)));

__device__ __forceinline__ ushort f2bf(float f) {
  union { float f; unsigned u; } x; x.f = f;
  unsigned r = x.u + 0x7fffu + ((x.u >> 16) & 1u);
  return (ushort)(r >> 16);
}
__device__ __forceinline__ float bf2f(ushort u) {
  union { unsigned u; float f; } x; x.u = ((unsigned)u) << 16; return x.f;
}

// ---- K1: fused [qk (blocks 0..31)] [w2tp pack (32..126)] [gather (127..18126)] ----
__global__ __launch_bounds__(256) void k_front(
    const float* __restrict__ voice, const int* __restrict__ sent,
    const float* __restrict__ W1, const float* __restrict__ b1,
    const int* __restrict__ widx, const float* __restrict__ emb,
    const float* __restrict__ W2,
    float* __restrict__ Aout, ushort* __restrict__ web, ushort* __restrict__ w2tp) {
  __shared__ float sq[SS][33];
  int blk = blockIdx.x, t = threadIdx.x;
  if (blk < 32) {
    int b = blk;
    for (int o = t; o < SS * HH; o += 256) {
      int s = o >> 5, j = o & 31;
      const float* vrow = voice + ((size_t)b * SS + s) * VDD;
      float acc = b1[j];
      #pragma unroll 8
      for (int d = 0; d < VDD; ++d) acc += vrow[d] * W1[d * HH + j];
      sq[s][j] = acc;
    }
    __syncthreads();
    int sn = sent[b];
    int wv = t >> 6, ln = t & 63;
    for (int q = wv; q < SS; q += 4) {
      float acc = 0.f;
      #pragma unroll
      for (int j = 0; j < HH; ++j) acc += sq[q][j] * sq[ln][j];
      if (ln >= sn) acc -= 1e12f;
      float mx = acc;
      #pragma unroll
      for (int off = 32; off; off >>= 1) mx = fmaxf(mx, __shfl_xor(mx, off));
      float e = expf(acc - mx);
      float sm = e;
      #pragma unroll
      for (int off = 32; off; off >>= 1) sm += __shfl_xor(sm, off);
      Aout[((size_t)b * SS + q) * SS + ln] = e / sm;
    }
  } else if (blk < 127) {
    int g = (blk - 32) * 256 + t;
    if (g < 380 * 64) {
      int tI = g >> 6, lane = g & 63;
      int kc2 = tI / 19, ms = tI - kc2 * 19;
      int kc = kc2 >> 1, ks = kc2 & 1;
      int lg = lane >> 4, lr = lane & 15;
      int e = ms * 16 + lr;
      int kp0 = kc * 64 + ks * 32 + lg * 8;
      ushort v[8];
      #pragma unroll
      for (int j = 0; j < 8; ++j) {
        int kp = kp0 + j;
        int c = kp < 320 ? kp : kp - 20;
        bool ok = (e < EE) && (kp < 320 ? kp < 300 : kp < 620);
        v[j] = ok ? f2bf(W2[(size_t)c * EE + e]) : (ushort)0;
      }
      ushort* dst = w2tp + (size_t)g * 8;
      *(ushort4*)dst = *(ushort4*)&v[0];
      *(ushort4*)(dst + 4) = *(ushort4*)&v[4];
    }
  } else {
    int tid = (blk - 127) * 256 + t;
    if (tid < BB * SS * WW * 75) {
      int row = tid / 75, p = tid - row * 75;
      int idx = widx[row];
      float4 v = *(const float4*)(emb + (size_t)idx * EE + p * 4);
      ushort4 o;
      o.x = f2bf(v.x); o.y = f2bf(v.y); o.z = f2bf(v.z); o.w = f2bf(v.w);
      *(ushort4*)(web + (size_t)row * EE + p * 4) = o;
    }
  }
}

// ---- K2: Obf = mask .* (A @ V) via MFMA; vt = V^T staged w/ XOR k-group swizzle ----
__global__ __launch_bounds__(256) void k_pv2(
    const float* __restrict__ Aout, const ushort* __restrict__ web,
    const int* __restrict__ sent, ushort* __restrict__ obf) {
  __shared__ ushort sa[64][72];    // A bf16 [q][k]
  __shared__ ushort vt[256][72];   // V^T [n_local][k], k-group g stored at g^((n>>3)&7)
  int nc = blockIdx.x, b = blockIdx.y, t = threadIdx.x;
  int n0blk = nc * 256;
  for (int i = t; i < 64 * 16; i += 256) {
    int q = i >> 4, c4 = (i & 15) << 2;
    float4 f = *(const float4*)(Aout + (size_t)b * 4096 + q * 64 + c4);
    ushort4 u; u.x = f2bf(f.x); u.y = f2bf(f.y); u.z = f2bf(f.z); u.w = f2bf(f.w);
    *(ushort4*)&sa[q][c4] = u;
  }
  int kk = t >> 5, nl0 = (t & 31) << 3;
  int swz = (t & 31) & 7;
  for (int p = 0; p < 8; ++p) {
    int k = p * 8 + kk;
    int n = n0blk + nl0;
    ushort v[8];
    if (n + 7 < 9000) {
      const ushort* s = web + (size_t)(b * 64 + k) * 9000 + n;
      *(ushort4*)&v[0] = *(const ushort4*)s;
      *(ushort4*)&v[4] = *(const ushort4*)(s + 4);
    } else {
      #pragma unroll
      for (int j = 0; j < 8; ++j) v[j] = 0;
    }
    int c = (((k >> 3) ^ swz) << 3) + (k & 7);
    #pragma unroll
    for (int j = 0; j < 8; ++j) vt[nl0 + j][c] = v[j];
  }
  __syncthreads();
  int sn = sent[b];
  int wv = t >> 6, ln = t & 63, lr = ln & 15, lg = ln >> 4;
  int nbase = wv * 64;
  f32x4 acc[4][4];
  #pragma unroll
  for (int mt = 0; mt < 4; ++mt)
    #pragma unroll
    for (int nf = 0; nf < 4; ++nf) acc[mt][nf] = (f32x4){0.f, 0.f, 0.f, 0.f};
  #pragma unroll
  for (int ks = 0; ks < 2; ++ks) {
    if (ks * 32 < sn) {
      bf16x8 bfrag[4];
      #pragma unroll
      for (int nf = 0; nf < 4; ++nf) {
        int row = nbase + nf * 16 + lr;
        int gp = (ks * 4 + lg) ^ ((row >> 3) & 7);
        bfrag[nf] = *(const bf16x8*)&vt[row][gp << 3];
      }
      #pragma unroll
      for (int mt = 0; mt < 4; ++mt) {
        if (mt * 16 < sn) {
          bf16x8 afrag = *(const bf16x8*)&sa[mt * 16 + lr][ks * 32 + lg * 8];
          #pragma unroll
          for (int nf = 0; nf < 4; ++nf)
            acc[mt][nf] = __builtin_amdgcn_mfma_f32_16x16x32_bf16(
                afrag, bfrag[nf], acc[mt][nf], 0, 0, 0);
        }
      }
    }
  }
  #pragma unroll
  for (int mt = 0; mt < 4; ++mt) {
    #pragma unroll
    for (int nf = 0; nf < 4; ++nf) {
      int n = n0blk + nbase + nf * 16 + lr;
      if (n < 9000) {
        #pragma unroll
        for (int j = 0; j < 4; ++j) {
          int q = mt * 16 + lg * 4 + j;
          obf[(size_t)(b * 64 + q) * 9000 + n] =
              (q < sn) ? f2bf(acc[mt][nf][j]) : (ushort)0;
        }
      }
    }
  }
}

// ---- K3: out = (concat @ W2 + b2) transposed; whole-phase LDS staging,
//      ZERO barriers inside the K-loop (2 per phase) ----
__global__ __launch_bounds__(256) void k_out3(
    const ushort* __restrict__ obf, const ushort* __restrict__ web,
    const ushort* __restrict__ w2tp, const float* __restrict__ b2,
    float* __restrict__ out) {
  __shared__ ushort sb[64][324];   // 64 rows x 320 cols (+4 pad); stride 162 words -> exact-8 b128 reads
  __shared__ float sb2[304];
  int blk = blockIdx.x, t = threadIdx.x;
  int wv = t >> 6, ln = t & 63;
  size_t r0 = (size_t)blk * 64;
  int bbat = blk / 30;
  int rin0 = (blk % 30) * 64;
  for (int i = t; i < 304; i += 256) sb2[i] = (i < 300) ? b2[i] : 0.f;
  f32x4 acc[5][4];
  #pragma unroll
  for (int i = 0; i < 5; ++i)
    #pragma unroll
    for (int nf = 0; nf < 4; ++nf) acc[i][nf] = (f32x4){0.f, 0.f, 0.f, 0.f};
  int lr = ln & 15, lg = ln >> 4;

  for (int ph = 0; ph < 2; ++ph) {
    const ushort* src = ph ? web : obf;
    // stage the whole 64x320 half-concat (cols >=300 zeroed)
    for (int i = t; i < 64 * 40; i += 256) {
      int row = i / 40, c8 = (i - row * 40) * 8;
      ushort4 lo = {0, 0, 0, 0}, hi = {0, 0, 0, 0};
      const ushort* s = src + (r0 + row) * 300 + c8;
      if (c8 + 8 <= 300) {
        lo = *(const ushort4*)s;
        hi = *(const ushort4*)(s + 4);
      } else if (c8 < 300) {      // c8 == 296: 4 valid ushorts, 8B-aligned
        lo = *(const ushort4*)s;
      }
      *(ushort4*)&sb[row][c8] = lo;
      *(ushort4*)&sb[row][c8 + 4] = hi;
    }
    __syncthreads();
    #pragma unroll
    for (int kc = 0; kc < 5; ++kc) {
      bf16x8 bfr[4][2];
      #pragma unroll
      for (int nf = 0; nf < 4; ++nf)
        #pragma unroll
        for (int ks = 0; ks < 2; ++ks)
          bfr[nf][ks] = *(const bf16x8*)&sb[nf * 16 + lr][kc * 64 + ks * 32 + lg * 8];
      #pragma unroll
      for (int i = 0; i < 5; ++i) {
        int ms = wv + 4 * i;
        if (ms < 19) {
          #pragma unroll
          for (int ks = 0; ks < 2; ++ks) {
            bf16x8 afr = *(const bf16x8*)(w2tp +
                ((size_t)(((ph * 5 + kc) * 2 + ks) * 19 + ms) * 64 + ln) * 8);
            #pragma unroll
            for (int nf = 0; nf < 4; ++nf)
              acc[i][nf] = __builtin_amdgcn_mfma_f32_16x16x32_bf16(
                  afr, bfr[nf][ks], acc[i][nf], 0, 0, 0);
          }
        }
      }
    }
    __syncthreads();   // protect sb before phase-1 restage
  }
  #pragma unroll
  for (int i = 0; i < 5; ++i) {
    int ms = wv + 4 * i;
    if (ms >= 19) continue;
    #pragma unroll
    for (int nf = 0; nf < 4; ++nf) {
      int rin = rin0 + nf * 16 + lr;
      #pragma unroll
      for (int j = 0; j < 4; ++j) {
        int e = ms * 16 + lg * 4 + j;
        if (e < 300)
          out[(size_t)(bbat * 300 + e) * 1920 + rin] = acc[i][nf][j] + sb2[e];
      }
    }
  }
}

extern "C" void kernel_launch(void* const* d_in, const int* in_sizes, int n_in,
                              void* d_out, int out_size, void* d_ws, size_t ws_size,
                              hipStream_t stream) {
  const int*   widx  = (const int*)d_in[0];
  const float* voice = (const float*)d_in[1];
  const int*   sent  = (const int*)d_in[2];
  const float* emb   = (const float*)d_in[4];
  const float* W1    = (const float*)d_in[5];
  const float* b1    = (const float*)d_in[6];
  const float* W2    = (const float*)d_in[7];
  const float* b2    = (const float*)d_in[8];
  float* out  = (float*)d_out;
  float* Aout = out + (size_t)BB * EE * SS * WW;  // O first, then A

  ushort* web  = (ushort*)d_ws;                   // [61440][300] bf16
  ushort* obf  = web + (size_t)18432000;          // [61440][300] bf16
  ushort* w2tp = obf + (size_t)18432000;          // [380][64][8] bf16 fragment-major

  hipLaunchKernelGGL(k_front, dim3(18127), dim3(256), 0, stream,
                     voice, sent, W1, b1, widx, emb, W2, Aout, web, w2tp);
  hipLaunchKernelGGL(k_pv2, dim3(36, BB), dim3(256), 0, stream, Aout, web, sent, obf);
  hipLaunchKernelGGL(k_out3, dim3(960), dim3(256), 0, stream, obf, web, w2tp, b2, out);
}

// Round 6
// 122.275 us; speedup vs baseline: 1.0818x; 1.0818x over previous
//
#include <hip/hip_runtime.h>

#define BB 32
#define SS 64
#define WW 30
#define EE 300
#define VDD 128
#define HH 32

typedef short bf16x8 __attribute__((ext_vector_type(8)));
typedef float f32x4 __attribute__((ext_vector_type(4)));

__device__ __forceinline__ ushort f2bf(float f) {
  union { float f; unsigned u; } x; x.f = f;
  unsigned r = x.u + 0x7fffu + ((x.u >> 16) & 1u);
  return (ushort)(r >> 16);
}
__device__ __forceinline__ float bf2f(ushort u) {
  union { unsigned u; float f; } x; x.u = ((unsigned)u) << 16; return x.f;
}

// ---- K1: fused [qk (blocks 0..31)] [w2tp pack (32..126)] [gather (127..18126)] ----
__global__ __launch_bounds__(256) void k_front(
    const float* __restrict__ voice, const int* __restrict__ sent,
    const float* __restrict__ W1, const float* __restrict__ b1,
    const int* __restrict__ widx, const float* __restrict__ emb,
    const float* __restrict__ W2,
    float* __restrict__ Aout, ushort* __restrict__ web, ushort* __restrict__ w2tp) {
  __shared__ float sq[SS][33];
  int blk = blockIdx.x, t = threadIdx.x;
  if (blk < 32) {
    int b = blk;
    for (int o = t; o < SS * HH; o += 256) {
      int s = o >> 5, j = o & 31;
      const float* vrow = voice + ((size_t)b * SS + s) * VDD;
      float acc = b1[j];
      #pragma unroll 8
      for (int d = 0; d < VDD; ++d) acc += vrow[d] * W1[d * HH + j];
      sq[s][j] = acc;
    }
    __syncthreads();
    int sn = sent[b];
    int wv = t >> 6, ln = t & 63;
    for (int q = wv; q < SS; q += 4) {
      float acc = 0.f;
      #pragma unroll
      for (int j = 0; j < HH; ++j) acc += sq[q][j] * sq[ln][j];
      if (ln >= sn) acc -= 1e12f;
      float mx = acc;
      #pragma unroll
      for (int off = 32; off; off >>= 1) mx = fmaxf(mx, __shfl_xor(mx, off));
      float e = expf(acc - mx);
      float sm = e;
      #pragma unroll
      for (int off = 32; off; off >>= 1) sm += __shfl_xor(sm, off);
      Aout[((size_t)b * SS + q) * SS + ln] = e / sm;
    }
  } else if (blk < 127) {
    int g = (blk - 32) * 256 + t;
    if (g < 380 * 64) {
      int tI = g >> 6, lane = g & 63;
      int kc2 = tI / 19, ms = tI - kc2 * 19;
      int kc = kc2 >> 1, ks = kc2 & 1;
      int lg = lane >> 4, lr = lane & 15;
      int e = ms * 16 + lr;
      int kp0 = kc * 64 + ks * 32 + lg * 8;
      ushort v[8];
      #pragma unroll
      for (int j = 0; j < 8; ++j) {
        int kp = kp0 + j;
        int c = kp < 320 ? kp : kp - 20;
        bool ok = (e < EE) && (kp < 320 ? kp < 300 : kp < 620);
        v[j] = ok ? f2bf(W2[(size_t)c * EE + e]) : (ushort)0;
      }
      ushort* dst = w2tp + (size_t)g * 8;
      *(ushort4*)dst = *(ushort4*)&v[0];
      *(ushort4*)(dst + 4) = *(ushort4*)&v[4];
    }
  } else {
    int tid = (blk - 127) * 256 + t;
    if (tid < BB * SS * WW * 75) {
      int row = tid / 75, p = tid - row * 75;
      int idx = widx[row];
      float4 v = *(const float4*)(emb + (size_t)idx * EE + p * 4);
      ushort4 o;
      o.x = f2bf(v.x); o.y = f2bf(v.y); o.z = f2bf(v.z); o.w = f2bf(v.w);
      *(ushort4*)(web + (size_t)row * EE + p * 4) = o;
    }
  }
}

// ---- K2: Obf = mask .* (A @ V) via MFMA; vt = V^T staged w/ XOR k-group swizzle ----
__global__ __launch_bounds__(256) void k_pv2(
    const float* __restrict__ Aout, const ushort* __restrict__ web,
    const int* __restrict__ sent, ushort* __restrict__ obf) {
  __shared__ ushort sa[64][72];    // A bf16 [q][k]
  __shared__ ushort vt[256][72];   // V^T [n_local][k], k-group g stored at g^((n>>3)&7)
  int nc = blockIdx.x, b = blockIdx.y, t = threadIdx.x;
  int n0blk = nc * 256;
  for (int i = t; i < 64 * 16; i += 256) {
    int q = i >> 4, c4 = (i & 15) << 2;
    float4 f = *(const float4*)(Aout + (size_t)b * 4096 + q * 64 + c4);
    ushort4 u; u.x = f2bf(f.x); u.y = f2bf(f.y); u.z = f2bf(f.z); u.w = f2bf(f.w);
    *(ushort4*)&sa[q][c4] = u;
  }
  int kk = t >> 5, nl0 = (t & 31) << 3;
  int swz = (t & 31) & 7;
  for (int p = 0; p < 8; ++p) {
    int k = p * 8 + kk;
    int n = n0blk + nl0;
    ushort v[8];
    if (n + 7 < 9000) {
      const ushort* s = web + (size_t)(b * 64 + k) * 9000 + n;
      *(ushort4*)&v[0] = *(const ushort4*)s;
      *(ushort4*)&v[4] = *(const ushort4*)(s + 4);
    } else {
      #pragma unroll
      for (int j = 0; j < 8; ++j) v[j] = 0;
    }
    int c = (((k >> 3) ^ swz) << 3) + (k & 7);
    #pragma unroll
    for (int j = 0; j < 8; ++j) vt[nl0 + j][c] = v[j];
  }
  __syncthreads();
  int sn = sent[b];
  int wv = t >> 6, ln = t & 63, lr = ln & 15, lg = ln >> 4;
  int nbase = wv * 64;
  f32x4 acc[4][4];
  #pragma unroll
  for (int mt = 0; mt < 4; ++mt)
    #pragma unroll
    for (int nf = 0; nf < 4; ++nf) acc[mt][nf] = (f32x4){0.f, 0.f, 0.f, 0.f};
  #pragma unroll
  for (int ks = 0; ks < 2; ++ks) {
    if (ks * 32 < sn) {
      bf16x8 bfrag[4];
      #pragma unroll
      for (int nf = 0; nf < 4; ++nf) {
        int row = nbase + nf * 16 + lr;
        int gp = (ks * 4 + lg) ^ ((row >> 3) & 7);
        bfrag[nf] = *(const bf16x8*)&vt[row][gp << 3];
      }
      #pragma unroll
      for (int mt = 0; mt < 4; ++mt) {
        if (mt * 16 < sn) {
          bf16x8 afrag = *(const bf16x8*)&sa[mt * 16 + lr][ks * 32 + lg * 8];
          #pragma unroll
          for (int nf = 0; nf < 4; ++nf)
            acc[mt][nf] = __builtin_amdgcn_mfma_f32_16x16x32_bf16(
                afrag, bfrag[nf], acc[mt][nf], 0, 0, 0);
        }
      }
    }
  }
  #pragma unroll
  for (int mt = 0; mt < 4; ++mt) {
    #pragma unroll
    for (int nf = 0; nf < 4; ++nf) {
      int n = n0blk + nbase + nf * 16 + lr;
      if (n < 9000) {
        #pragma unroll
        for (int j = 0; j < 4; ++j) {
          int q = mt * 16 + lg * 4 + j;
          obf[(size_t)(b * 64 + q) * 9000 + n] =
              (q < sn) ? f2bf(acc[mt][nf][j]) : (ushort)0;
        }
      }
    }
  }
}

// ---- K3: 8-wave version. 64-row tile, whole-phase staging, wave wv owns
//      ms in {wv, wv+8, wv+16}: acc 48 VGPR, short afr chains, 16 waves/CU ----
__global__ __launch_bounds__(512, 4) void k_out4(
    const ushort* __restrict__ obf, const ushort* __restrict__ web,
    const ushort* __restrict__ w2tp, const float* __restrict__ b2,
    float* __restrict__ out) {
  __shared__ ushort sb[64][324];   // stride 162 words == 2 mod 32 -> 2-way (free)
  __shared__ float sb2[304];
  int blk = blockIdx.x, t = threadIdx.x;
  int wv = t >> 6, ln = t & 63;
  size_t r0 = (size_t)blk * 64;
  int bbat = blk / 30;
  int rin0 = (blk % 30) * 64;
  for (int i = t; i < 304; i += 512) sb2[i] = (i < 300) ? b2[i] : 0.f;
  f32x4 acc[3][4];
  #pragma unroll
  for (int i = 0; i < 3; ++i)
    #pragma unroll
    for (int nf = 0; nf < 4; ++nf) acc[i][nf] = (f32x4){0.f, 0.f, 0.f, 0.f};
  int lr = ln & 15, lg = ln >> 4;

  for (int ph = 0; ph < 2; ++ph) {
    const ushort* src = ph ? web : obf;
    // stage the whole 64x320 half-concat (cols >=300 zeroed); 5 iters/thread
    for (int i = t; i < 64 * 40; i += 512) {
      int row = i / 40, c8 = (i - row * 40) * 8;
      ushort4 lo = {0, 0, 0, 0}, hi = {0, 0, 0, 0};
      const ushort* s = src + (r0 + row) * 300 + c8;
      if (c8 + 8 <= 300) {
        lo = *(const ushort4*)s;
        hi = *(const ushort4*)(s + 4);
      } else if (c8 < 300) {      // c8 == 296: 4 valid ushorts
        lo = *(const ushort4*)s;
      }
      *(ushort4*)&sb[row][c8] = lo;
      *(ushort4*)&sb[row][c8 + 4] = hi;
    }
    __syncthreads();
    #pragma unroll
    for (int kc = 0; kc < 5; ++kc) {
      bf16x8 bfr[4][2];
      #pragma unroll
      for (int nf = 0; nf < 4; ++nf)
        #pragma unroll
        for (int ks = 0; ks < 2; ++ks)
          bfr[nf][ks] = *(const bf16x8*)&sb[nf * 16 + lr][kc * 64 + ks * 32 + lg * 8];
      #pragma unroll
      for (int i = 0; i < 3; ++i) {
        int ms = wv + 8 * i;
        if (ms < 19) {
          #pragma unroll
          for (int ks = 0; ks < 2; ++ks) {
            bf16x8 afr = *(const bf16x8*)(w2tp +
                ((size_t)(((ph * 5 + kc) * 2 + ks) * 19 + ms) * 64 + ln) * 8);
            #pragma unroll
            for (int nf = 0; nf < 4; ++nf)
              acc[i][nf] = __builtin_amdgcn_mfma_f32_16x16x32_bf16(
                  afr, bfr[nf][ks], acc[i][nf], 0, 0, 0);
          }
        }
      }
    }
    __syncthreads();   // protect sb before phase-1 restage
  }
  #pragma unroll
  for (int i = 0; i < 3; ++i) {
    int ms = wv + 8 * i;
    if (ms >= 19) continue;
    #pragma unroll
    for (int nf = 0; nf < 4; ++nf) {
      int rin = rin0 + nf * 16 + lr;
      #pragma unroll
      for (int j = 0; j < 4; ++j) {
        int e = ms * 16 + lg * 4 + j;
        if (e < 300)
          out[(size_t)(bbat * 300 + e) * 1920 + rin] = acc[i][nf][j] + sb2[e];
      }
    }
  }
}

extern "C" void kernel_launch(void* const* d_in, const int* in_sizes, int n_in,
                              void* d_out, int out_size, void* d_ws, size_t ws_size,
                              hipStream_t stream) {
  const int*   widx  = (const int*)d_in[0];
  const float* voice = (const float*)d_in[1];
  const int*   sent  = (const int*)d_in[2];
  const float* emb   = (const float*)d_in[4];
  const float* W1    = (const float*)d_in[5];
  const float* b1    = (const float*)d_in[6];
  const float* W2    = (const float*)d_in[7];
  const float* b2    = (const float*)d_in[8];
  float* out  = (float*)d_out;
  float* Aout = out + (size_t)BB * EE * SS * WW;  // O first, then A

  ushort* web  = (ushort*)d_ws;                   // [61440][300] bf16
  ushort* obf  = web + (size_t)18432000;          // [61440][300] bf16
  ushort* w2tp = obf + (size_t)18432000;          // [380][64][8] bf16 fragment-major

  hipLaunchKernelGGL(k_front, dim3(18127), dim3(256), 0, stream,
                     voice, sent, W1, b1, widx, emb, W2, Aout, web, w2tp);
  hipLaunchKernelGGL(k_pv2, dim3(36, BB), dim3(256), 0, stream, Aout, web, sent, obf);
  hipLaunchKernelGGL(k_out4, dim3(960), dim3(512), 0, stream, obf, web, w2tp, b2, out);
}